// Round 6
// baseline (187.894 us; speedup 1.0000x reference)
//
#include <hip/hip_runtime.h>
#include <hip/hip_bf16.h>
#include <math.h>

// Problem constants
#define L_SEQ   1024
#define NB      8
#define H_DIM   300
#define KWIN    5
#define NREL    11          // 2K+1
#define PDIM    50
#define NC      11234       // band pair count for L=1024, K=5
#define BNC     (NB*NC)     // 89872
#define LN_EPS  1e-5f

#define KPAD    320         // K padded with zeros in [300,320)
#define WKSTR   320         // Wb k-stride (shorts)
#define WNPAD   320         // Wb padded n rows

#define ITILE   8           // i rows per block
#define HROWS   18          // hc halo rows: i0-5 .. i0+12
#define XROWS   48          // rows 0..7 he (8..15 pad), 16..33 hc (34..47 pad)
#define XSTR    328         // X row stride in shorts
#define PRELSTR 320         // padded prel row stride (floats)

// Workspace layout (float offsets)
#define PREL_OFF  0                         // 11*320 = 3520 -> pad 3584
#define WB_OFF    3584                      // 2*320*320 shorts = 102400 floats

typedef __attribute__((ext_vector_type(8))) short s16x8;
typedef __attribute__((ext_vector_type(4))) short s16x4;
typedef __attribute__((ext_vector_type(4))) float f32x4;

__device__ __forceinline__ short f2bf(float f) {
    unsigned u = __float_as_uint(f);
    u += 0x7fffu + ((u >> 16) & 1u);
    return (short)(u >> 16);
}
__device__ __forceinline__ float bf2f(short s) {
    return __uint_as_float(((unsigned)(unsigned short)s) << 16);
}

// band row start: first linear index n of row i
__device__ __forceinline__ int rowstart(int i) {
    if (i < 5)     return 6 * i + (i * (i - 1)) / 2;
    if (i <= 1018) return 40 + (i - 5) * 11;
    int d = i - 1019;
    return 11194 + d * 10 - (d * (d - 1)) / 2;
}

// ---------------------------------------------------------------------------
// Kernel 1: prep.
//  blocks 0..13   : prelP[r][h] (stride 320, zero pad h>=300)
//  blocks 14..813 : Wb[z][n][k] = bf16(W1[n][z*300+k]), zero-padded
__global__ __launch_bounds__(256) void prep_kernel(
    const float* __restrict__ pos_W, const float* __restrict__ W1,
    const float* __restrict__ b1, float* __restrict__ prel,
    short* __restrict__ Wb)
{
    if (blockIdx.x < 14) {
        __shared__ float semb[NREL * PDIM];
        for (int t = threadIdx.x; t < NREL * PDIM; t += 256) {
            int r = t / PDIM, d = t % PDIM;
            float acc = 0.f;
#pragma unroll
            for (int r2 = 0; r2 < NREL; ++r2) {
                float cnt = (float)(L_SEQ - abs(r2 - KWIN));
                int dr = r - r2;
                acc += cnt * expf(-(float)(dr * dr)) * pos_W[r2 * PDIM + d];
            }
            semb[t] = acc;
        }
        __syncthreads();
        int t = blockIdx.x * 256 + threadIdx.x;
        if (t < NREL * PRELSTR) {
            int r = t / PRELSTR, h = t % PRELSTR;
            float acc = 0.f;
            if (h < H_DIM) {
                acc = b1[h];
                const float* wrow = W1 + (size_t)h * 650 + 600;
                const float* em = semb + r * PDIM;
#pragma unroll 10
                for (int d = 0; d < PDIM; ++d) acc += wrow[d] * em[d];
            }
            prel[t] = acc;
        }
    } else {
        int id = (blockIdx.x - 14) * 256 + threadIdx.x;
        if (id < 2 * WNPAD * WKSTR) {
            int z = id / (WNPAD * WKSTR);
            int rem = id % (WNPAD * WKSTR);
            int n = rem / WKSTR, k = rem % WKSTR;
            float v = (n < H_DIM && k < H_DIM) ? W1[(size_t)n * 650 + z * H_DIM + k] : 0.f;
            Wb[id] = f2bf(v);
        }
    }
}

// ---------------------------------------------------------------------------
// Kernel 2: fused GEMM + epilogue. Block = (b, i-tile of 8). 256 threads.
// __launch_bounds__(256,4): VGPR<=128 -> 4 blocks/CU resident (grid 1024).
__global__ __launch_bounds__(256, 4) void fused_kernel(
    const float* __restrict__ h_e, const float* __restrict__ h_c,
    const float* __restrict__ h_share, const short* __restrict__ Wb,
    const float* __restrict__ prel,
    const float* __restrict__ ln_g, const float* __restrict__ ln_b,
    const float* __restrict__ W2, const float* __restrict__ b2,
    float* __restrict__ out, float* __restrict__ posout)
{
    __shared__ __align__(16) short X[XROWS * XSTR];   // 31488 B
    __shared__ __align__(16) float SG[PRELSTR];       // ln_g zero-padded
    __shared__ __align__(16) float SB[PRELSTR];       // ln_b
    __shared__ __align__(16) float SW[PRELSTR];       // W2

    const int tid = threadIdx.x;
    const int b   = blockIdx.x >> 7;          // 128 i-tiles
    const int i0  = (blockIdx.x & 127) * ITILE;

    // ---- zero pad: rows 8..15 & 34..47 full width; cols [304,328) of data rows
    for (int t = tid; t < 980; t += 256) {
        int row, c;
        if (t < 902) {                         // 22 pad rows x 41 chunks
            int rr = t / 41; c = (t % 41) * 8;
            row = rr < 8 ? 8 + rr : 34 + (rr - 8);
        } else {                               // 26 data rows x 3 chunks
            int u = t - 902; int r3 = u / 3;
            row = r3 < 8 ? r3 : 16 + (r3 - 8);
            c = 304 + (u % 3) * 8;
        }
        *(s16x8*)&X[row * XSTR + c] = (s16x8){0,0,0,0,0,0,0,0};
    }
    // ---- LN params to LDS (zero pad to 320)
    for (int t = tid; t < PRELSTR; t += 256) {
        bool v = t < H_DIM;
        SG[t] = v ? ln_g[t] : 0.f;
        SB[t] = v ? ln_b[t] : 0.f;
        SW[t] = v ? W2[t]   : 0.f;
    }
    // ---- stage: loop over 18 halo rows; h_share read ONCE per row.
    for (int t = tid; t < HROWS * 76; t += 256) {
        int s = t / 76, kc = (t % 76) * 4;
        int g = i0 - KWIN + s;
        bool valid = (kc < H_DIM) && (g >= 0) && (g < L_SEQ);
        float4 hs4 = make_float4(0.f,0.f,0.f,0.f), hc4 = hs4;
        size_t off = 0;
        if (valid) {
            off = ((size_t)b * L_SEQ + g) * H_DIM + kc;
            hs4 = *(const float4*)(h_share + off);
            hc4 = *(const float4*)(h_c + off);
        }
        s16x4 vc = { f2bf(hc4.x + hs4.x), f2bf(hc4.y + hs4.y),
                     f2bf(hc4.z + hs4.z), f2bf(hc4.w + hs4.w) };
        *(s16x4*)&X[(16 + s) * XSTR + kc] = vc;
        if (s >= 5 && s < 5 + ITILE) {         // he rows: g = i0 + (s-5)
            float4 he4 = make_float4(0.f,0.f,0.f,0.f);
            if (valid) he4 = *(const float4*)(h_e + off);
            s16x4 ve = { f2bf(he4.x + hs4.x), f2bf(he4.y + hs4.y),
                         f2bf(he4.z + hs4.z), f2bf(he4.w + hs4.w) };
            *(s16x4*)&X[(s - 5) * XSTR + kc] = ve;
        }
    }
    __syncthreads();

    // ---- GEMM phase. 4 waves; wave = 80-wide n-slice; 3 m-frags x 5 n-frags.
    //   m-frag 0: X rows 0..15 (he, z=0); m-frags 1,2: rows 16..31, 32..47 (hc, z=1)
    const int wave = tid >> 6, lane = tid & 63;
    const int fr = lane & 15, fq = lane >> 4;
    const int nsl = wave * 80;
    const short* wb0 = Wb + ((size_t)(nsl + fr)) * WKSTR + fq * 8;          // z=0
    const short* wb1 = Wb + ((size_t)(WNPAD + nsl + fr)) * WKSTR + fq * 8;  // z=1

    f32x4 acc[3][5] = {};

#pragma unroll 2
    for (int k0 = 0; k0 < KPAD; k0 += 32) {
        s16x8 a0 = *(const s16x8*)&X[(fr)      * XSTR + k0 + fq * 8];
        s16x8 a1 = *(const s16x8*)&X[(16 + fr) * XSTR + k0 + fq * 8];
        s16x8 a2 = *(const s16x8*)&X[(32 + fr) * XSTR + k0 + fq * 8];
#pragma unroll
        for (int nt = 0; nt < 5; ++nt) {
            s16x8 b0 = *(const s16x8*)(wb0 + (size_t)nt * 16 * WKSTR + k0);
            s16x8 b1 = *(const s16x8*)(wb1 + (size_t)nt * 16 * WKSTR + k0);
            acc[0][nt] = __builtin_amdgcn_mfma_f32_16x16x32_bf16(a0, b0, acc[0][nt], 0, 0, 0);
            acc[1][nt] = __builtin_amdgcn_mfma_f32_16x16x32_bf16(a1, b1, acc[1][nt], 0, 0, 0);
            acc[2][nt] = __builtin_amdgcn_mfma_f32_16x16x32_bf16(a2, b1, acc[2][nt], 0, 0, 0);
        }
    }
    __syncthreads();   // all waves done reading X inputs

    // ---- write results into X (bf16), unconditional (pad cols/rows -> zeros)
#pragma unroll
    for (int mf = 0; mf < 3; ++mf) {
#pragma unroll
        for (int nt = 0; nt < 5; ++nt) {
            const int col = nsl + nt * 16 + fr;
            const int rb  = mf * 16 + fq * 4;
#pragma unroll
            for (int r2 = 0; r2 < 4; ++r2)
                X[(rb + r2) * XSTR + col] = f2bf(acc[mf][nt][r2]);
        }
    }
    __syncthreads();

    // ---- Epilogue: 2 pairs per 16-lane quad, 3 rounds (88 pairs).
    const int quad = lane >> 4, fl = lane & 15;
    const int qq = wave * 4 + quad;            // 0..15
    const float b2v = b2[0];
    const float inv = 1.f / (float)H_DIM;

    for (int round = 0; round < 3; ++round) {
        const int qb = round * 32 + qq * 2;
        int di[2], rr[2], jj[2], ii[2];
        bool act[2];
#pragma unroll
        for (int u = 0; u < 2; ++u) {
            int q = qb + u;
            int qc = q < ITILE * NREL - 1 ? q : ITILE * NREL - 1;
            di[u] = qc / NREL; rr[u] = qc % NREL;
            ii[u] = i0 + di[u];
            jj[u] = ii[u] - KWIN + rr[u];
            act[u] = (q < ITILE * NREL) && (jj[u] >= 0) && (jj[u] < L_SEQ);
        }

        float h0[20], h1[20];
        float s0 = 0.f, ss0 = 0.f, s1 = 0.f, ss1 = 0.f;
#pragma unroll
        for (int w5 = 0; w5 < 5; ++w5) {
            const int c = w5 * 64 + fl * 4;
            // pair 0
            {
                s16x4 ea = *(const s16x4*)&X[di[0] * XSTR + c];
                s16x4 ca = *(const s16x4*)&X[(16 + di[0] + rr[0]) * XSTR + c];
                float4 p = *(const float4*)(prel + rr[0] * PRELSTR + c);
                float v0 = bf2f(ea.x) + bf2f(ca.x) + p.x;
                float v1 = bf2f(ea.y) + bf2f(ca.y) + p.y;
                float v2 = bf2f(ea.z) + bf2f(ca.z) + p.z;
                float v3 = bf2f(ea.w) + bf2f(ca.w) + p.w;
                h0[w5*4+0]=v0; h0[w5*4+1]=v1; h0[w5*4+2]=v2; h0[w5*4+3]=v3;
                s0 += v0 + v1 + v2 + v3;
                ss0 = fmaf(v0,v0,ss0); ss0 = fmaf(v1,v1,ss0);
                ss0 = fmaf(v2,v2,ss0); ss0 = fmaf(v3,v3,ss0);
            }
            // pair 1
            {
                s16x4 ea = *(const s16x4*)&X[di[1] * XSTR + c];
                s16x4 ca = *(const s16x4*)&X[(16 + di[1] + rr[1]) * XSTR + c];
                float4 p = *(const float4*)(prel + rr[1] * PRELSTR + c);
                float v0 = bf2f(ea.x) + bf2f(ca.x) + p.x;
                float v1 = bf2f(ea.y) + bf2f(ca.y) + p.y;
                float v2 = bf2f(ea.z) + bf2f(ca.z) + p.z;
                float v3 = bf2f(ea.w) + bf2f(ca.w) + p.w;
                h1[w5*4+0]=v0; h1[w5*4+1]=v1; h1[w5*4+2]=v2; h1[w5*4+3]=v3;
                s1 += v0 + v1 + v2 + v3;
                ss1 = fmaf(v0,v0,ss1); ss1 = fmaf(v1,v1,ss1);
                ss1 = fmaf(v2,v2,ss1); ss1 = fmaf(v3,v3,ss1);
            }
        }
#pragma unroll
        for (int off = 1; off < 16; off <<= 1) {
            s0  += __shfl_xor(s0,  off);
            s1  += __shfl_xor(s1,  off);
            ss0 += __shfl_xor(ss0, off);
            ss1 += __shfl_xor(ss1, off);
        }
        const float mu0   = s0 * inv;
        const float rsig0 = rsqrtf(ss0 * inv - mu0 * mu0 + LN_EPS);
        const float mu1   = s1 * inv;
        const float rsig1 = rsqrtf(ss1 * inv - mu1 * mu1 + LN_EPS);

        float acc0 = 0.f, acc1 = 0.f;
#pragma unroll
        for (int w5 = 0; w5 < 5; ++w5) {
            const int c = w5 * 64 + fl * 4;
            float4 g = *(const float4*)&SG[c];
            float4 bb = *(const float4*)&SB[c];
            float4 w = *(const float4*)&SW[c];
#pragma unroll
            for (int e = 0; e < 4; ++e) {
                float ge = (&g.x)[e], be = (&bb.x)[e], we = (&w.x)[e];
                float t0 = fmaf((h0[w5*4+e] - mu0) * rsig0, ge, be);
                float t1 = fmaf((h1[w5*4+e] - mu1) * rsig1, ge, be);
                t0 = t0 > 0.f ? t0 : __expf(t0) - 1.f;
                t1 = t1 > 0.f ? t1 : __expf(t1) - 1.f;
                acc0 = fmaf(t0, we, acc0);
                acc1 = fmaf(t1, we, acc1);
            }
        }
#pragma unroll
        for (int off = 1; off < 16; off <<= 1) {
            acc0 += __shfl_xor(acc0, off);
            acc1 += __shfl_xor(acc1, off);
        }

        if (fl == 0) {
#pragma unroll
            for (int u = 0; u < 2; ++u) {
                if (act[u]) {
                    const int jb = ii[u] - KWIN < 0 ? 0 : ii[u] - KWIN;
                    const int n = rowstart(ii[u]) + (jj[u] - jb);
                    out[(size_t)b * NC + n] = (u ? acc1 : acc0) + b2v;
                    if (b == 0) {
                        posout[2 * (size_t)n]     = (float)(ii[u] + 1);
                        posout[2 * (size_t)n + 1] = (float)(jj[u] + 1);
                    }
                }
            }
        }
    }
}

// ---------------------------------------------------------------------------
extern "C" void kernel_launch(void* const* d_in, const int* in_sizes, int n_in,
                              void* d_out, int out_size, void* d_ws, size_t ws_size,
                              hipStream_t stream) {
    const float* h_e     = (const float*)d_in[0];
    const float* h_c     = (const float*)d_in[1];
    const float* h_share = (const float*)d_in[2];
    // d_in[3] = mask (unused)
    const float* pos_W   = (const float*)d_in[4];
    const float* W1      = (const float*)d_in[5];
    const float* b1      = (const float*)d_in[6];
    const float* ln_g    = (const float*)d_in[7];
    const float* ln_b    = (const float*)d_in[8];
    const float* W2      = (const float*)d_in[9];
    const float* b2      = (const float*)d_in[10];

    float* ws   = (float*)d_ws;
    float* prel = ws + PREL_OFF;
    short* Wb   = (short*)(ws + WB_OFF);

    float* out    = (float*)d_out;
    float* posout = out + BNC;

    prep_kernel<<<14 + (2 * WNPAD * WKSTR) / 256, 256, 0, stream>>>(
        pos_W, W1, b1, prel, Wb);

    fused_kernel<<<NB * (L_SEQ / ITILE), 256, 0, stream>>>(
        h_e, h_c, h_share, Wb, prel, ln_g, ln_b, W2, b2, out, posout);
}

// Round 7
// 151.930 us; speedup vs baseline: 1.2367x; 1.2367x over previous
//
#include <hip/hip_runtime.h>
#include <hip/hip_bf16.h>
#include <math.h>

// Problem constants
#define L_SEQ   1024
#define NB      8
#define H_DIM   300
#define KWIN    5
#define NREL    11          // 2K+1
#define PDIM    50
#define NC      11234       // band pair count for L=1024, K=5
#define BNC     (NB*NC)     // 89872
#define LN_EPS  1e-5f

#define KPAD    320         // K padded with zeros in [300,320)
#define WKSTR   320         // Wb k-stride (shorts)
#define WNPAD   320         // Wb padded n rows

#define ITILE   8           // i rows per block
#define HROWS   18          // hc halo rows: i0-5 .. i0+12
#define ZROW    26          // LDS zero row index
#define XROWS   27          // 0..7 he, 8..25 hc, 26 zero
#define XSTR    328         // X row stride in shorts
#define PRELSTR 320         // padded prel row stride (floats)

// Workspace layout (float offsets)
#define PREL_OFF  0                         // 11*320 = 3520 -> pad 3584
#define WB_OFF    3584                      // 2*320*320 shorts = 102400 floats

typedef __attribute__((ext_vector_type(8))) short s16x8;
typedef __attribute__((ext_vector_type(4))) short s16x4;
typedef __attribute__((ext_vector_type(4))) float f32x4;

__device__ __forceinline__ short f2bf(float f) {
    unsigned u = __float_as_uint(f);
    u += 0x7fffu + ((u >> 16) & 1u);
    return (short)(u >> 16);
}
__device__ __forceinline__ float bf2f(short s) {
    return __uint_as_float(((unsigned)(unsigned short)s) << 16);
}

// band row start: first linear index n of row i
__device__ __forceinline__ int rowstart(int i) {
    if (i < 5)     return 6 * i + (i * (i - 1)) / 2;
    if (i <= 1018) return 40 + (i - 5) * 11;
    int d = i - 1019;
    return 11194 + d * 10 - (d * (d - 1)) / 2;
}

// ---------------------------------------------------------------------------
// Kernel 1: prep.
//  blocks 0..13   : prelP[r][h] (stride 320, zero pad h>=300)
//  blocks 14..813 : Wb[z][n][k] = bf16(W1[n][z*300+k]), zero-padded
__global__ __launch_bounds__(256) void prep_kernel(
    const float* __restrict__ pos_W, const float* __restrict__ W1,
    const float* __restrict__ b1, float* __restrict__ prel,
    short* __restrict__ Wb)
{
    if (blockIdx.x < 14) {
        __shared__ float semb[NREL * PDIM];
        for (int t = threadIdx.x; t < NREL * PDIM; t += 256) {
            int r = t / PDIM, d = t % PDIM;
            float acc = 0.f;
#pragma unroll
            for (int r2 = 0; r2 < NREL; ++r2) {
                float cnt = (float)(L_SEQ - abs(r2 - KWIN));
                int dr = r - r2;
                acc += cnt * expf(-(float)(dr * dr)) * pos_W[r2 * PDIM + d];
            }
            semb[t] = acc;
        }
        __syncthreads();
        int t = blockIdx.x * 256 + threadIdx.x;
        if (t < NREL * PRELSTR) {
            int r = t / PRELSTR, h = t % PRELSTR;
            float acc = 0.f;
            if (h < H_DIM) {
                acc = b1[h];
                const float* wrow = W1 + (size_t)h * 650 + 600;
                const float* em = semb + r * PDIM;
#pragma unroll 10
                for (int d = 0; d < PDIM; ++d) acc += wrow[d] * em[d];
            }
            prel[t] = acc;
        }
    } else {
        int id = (blockIdx.x - 14) * 256 + threadIdx.x;
        if (id < 2 * WNPAD * WKSTR) {
            int z = id / (WNPAD * WKSTR);
            int rem = id % (WNPAD * WKSTR);
            int n = rem / WKSTR, k = rem % WKSTR;
            float v = (n < H_DIM && k < H_DIM) ? W1[(size_t)n * 650 + z * H_DIM + k] : 0.f;
            Wb[id] = f2bf(v);
        }
    }
}

// ---------------------------------------------------------------------------
// Kernel 2: fused GEMM + epilogue. Block = (b, i-tile of 8). 512 threads.
// Grid 1024 -> 4 blocks/CU (waves-limited). No VGPR cap: round-5 shape
// compiled to 60 VGPR; spills (round 6) must not recur.
__global__ __launch_bounds__(512) void fused_kernel(
    const float* __restrict__ h_e, const float* __restrict__ h_c,
    const float* __restrict__ h_share, const short* __restrict__ Wb,
    const float* __restrict__ prel,
    const float* __restrict__ ln_g, const float* __restrict__ ln_b,
    const float* __restrict__ W2, const float* __restrict__ b2,
    float* __restrict__ out, float* __restrict__ posout)
{
    __shared__ __align__(16) short X[XROWS * XSTR];   // 17712 B
    __shared__ __align__(16) float SG[PRELSTR];       // ln_g zero-padded
    __shared__ __align__(16) float SB[PRELSTR];       // ln_b
    __shared__ __align__(16) float SW[PRELSTR];       // W2

    const int tid = threadIdx.x;
    const int b   = blockIdx.x >> 7;          // 128 i-tiles per batch
    const int i0  = (blockIdx.x & 127) * ITILE;

    // ---- zero-fill: all rows cols [304,328) (81 chunks) + zero row cols [0,304) (38)
    for (int t = tid; t < 119; t += 512) {
        int row, c;
        if (t < 81) { row = t / 3;  c = 304 + (t % 3) * 8; }
        else        { row = ZROW;   c = (t - 81) * 8; }
        *(s16x8*)&X[row * XSTR + c] = (s16x8){0,0,0,0,0,0,0,0};
    }
    // ---- LN params to LDS (zero pad to 320)
    for (int t = tid; t < PRELSTR; t += 512) {
        bool v = t < H_DIM;
        SG[t] = v ? ln_g[t] : 0.f;
        SB[t] = v ? ln_b[t] : 0.f;
        SW[t] = v ? W2[t]   : 0.f;
    }
    // ---- stage 18 halo rows; h_share read once per row.
    //  X rows 0..7  = bf16(he+hs)[i0+r]
    //  X rows 8..25 = bf16(hc+hs)[i0-5+s]
    for (int t = tid; t < HROWS * 76; t += 512) {
        int s = t / 76, kc = (t % 76) * 4;
        int g = i0 - KWIN + s;
        bool valid = (kc < H_DIM) && (g >= 0) && (g < L_SEQ);
        float4 hs4 = make_float4(0.f,0.f,0.f,0.f), hc4 = hs4;
        size_t off = 0;
        if (valid) {
            off = ((size_t)b * L_SEQ + g) * H_DIM + kc;
            hs4 = *(const float4*)(h_share + off);
            hc4 = *(const float4*)(h_c + off);
        }
        s16x4 vc = { f2bf(hc4.x + hs4.x), f2bf(hc4.y + hs4.y),
                     f2bf(hc4.z + hs4.z), f2bf(hc4.w + hs4.w) };
        *(s16x4*)&X[(8 + s) * XSTR + kc] = vc;
        if (s >= 5 && s < 5 + ITILE) {         // he row: g = i0 + (s-5)
            float4 he4 = make_float4(0.f,0.f,0.f,0.f);
            if (valid) he4 = *(const float4*)(h_e + off);
            s16x4 ve = { f2bf(he4.x + hs4.x), f2bf(he4.y + hs4.y),
                         f2bf(he4.z + hs4.z), f2bf(he4.w + hs4.w) };
            *(s16x4*)&X[(s - 5) * XSTR + kc] = ve;
        }
    }
    __syncthreads();

    // ---- GEMM. 8 waves: wz = wave>>2 (0: he frag, 1: hc frags), 80-wide n-slice.
    const int wave = tid >> 6, lane = tid & 63;
    const int fr = lane & 15, fq = lane >> 4;
    const int wz  = wave >> 2;
    const int nsl = (wave & 3) * 80;
    const short* wbase = Wb + ((size_t)(wz * WNPAD + nsl + fr)) * WKSTR + fq * 8;

    // A-frag row mapping with zero-row clamp for pad lanes
    const int mrow0 = wz ? (8 + fr) : (fr < ITILE ? fr : ZROW);
    const int mrow1 = (fr < 2) ? (24 + fr) : ZROW;   // wz==1 only

    f32x4 acc0[5] = {};
    f32x4 acc1[5] = {};

    for (int k0 = 0; k0 < KPAD; k0 += 32) {
        s16x8 bf[5];
#pragma unroll
        for (int nt = 0; nt < 5; ++nt)
            bf[nt] = *(const s16x8*)(wbase + (size_t)nt * 16 * WKSTR + k0);
        s16x8 af0 = *(const s16x8*)&X[mrow0 * XSTR + k0 + fq * 8];
#pragma unroll
        for (int nt = 0; nt < 5; ++nt)
            acc0[nt] = __builtin_amdgcn_mfma_f32_16x16x32_bf16(af0, bf[nt], acc0[nt], 0, 0, 0);
        if (wz) {
            s16x8 af1 = *(const s16x8*)&X[mrow1 * XSTR + k0 + fq * 8];
#pragma unroll
            for (int nt = 0; nt < 5; ++nt)
                acc1[nt] = __builtin_amdgcn_mfma_f32_16x16x32_bf16(af1, bf[nt], acc1[nt], 0, 0, 0);
        }
    }
    __syncthreads();   // all waves done reading X inputs

    // ---- write results into X (bf16). C/D layout: col=lane&15->fr, row=fq*4+r2.
    //  wz0: Ae rows 0..7 (guard fq<2);  wz1: Ac rows 8..25
#pragma unroll
    for (int nt = 0; nt < 5; ++nt) {
        const int col = nsl + nt * 16 + fr;     // 0..319, zeros for col>=300
        if (!wz) {
            if (fq < 2) {
#pragma unroll
                for (int r2 = 0; r2 < 4; ++r2)
                    X[(fq * 4 + r2) * XSTR + col] = f2bf(acc0[nt][r2]);
            }
        } else {
#pragma unroll
            for (int r2 = 0; r2 < 4; ++r2)
                X[(8 + fq * 4 + r2) * XSTR + col] = f2bf(acc0[nt][r2]);
            if (fq == 0) {
#pragma unroll
                for (int r2 = 0; r2 < 2; ++r2)
                    X[(24 + r2) * XSTR + col] = f2bf(acc1[nt][r2]);
            }
        }
    }
    __syncthreads();

    // ---- Epilogue: 1 pair per 16-lane quad, 32 quads, 3 rounds (88 pairs).
    const int quad = lane >> 4, fl = lane & 15;
    const int qq = wave * 4 + quad;            // 0..31
    const float b2v = b2[0];
    const float inv = 1.f / (float)H_DIM;

    for (int round = 0; round < 3; ++round) {
        const int q = round * 32 + qq;          // 0..95
        const int qc = q < ITILE * NREL - 1 ? q : ITILE * NREL - 1;
        const int di = qc / NREL, rr = qc % NREL;
        const int ii = i0 + di, j = ii - KWIN + rr;
        const bool active = (q < ITILE * NREL) && (j >= 0) && (j < L_SEQ);

        const int ea_off = di * XSTR;
        const int ca_off = (8 + di + rr) * XSTR;
        const float* prow = prel + rr * PRELSTR;

        float h[20];
        float s = 0.f, ss = 0.f;
#pragma unroll
        for (int w5 = 0; w5 < 5; ++w5) {
            const int c = w5 * 64 + fl * 4;     // 0..316; X/prel zero-padded
            s16x4 ea = *(const s16x4*)&X[ea_off + c];
            s16x4 ca = *(const s16x4*)&X[ca_off + c];
            float4 p = *(const float4*)(prow + c);
            float v0 = bf2f(ea.x) + bf2f(ca.x) + p.x;
            float v1 = bf2f(ea.y) + bf2f(ca.y) + p.y;
            float v2 = bf2f(ea.z) + bf2f(ca.z) + p.z;
            float v3 = bf2f(ea.w) + bf2f(ca.w) + p.w;
            h[w5*4+0]=v0; h[w5*4+1]=v1; h[w5*4+2]=v2; h[w5*4+3]=v3;
            s += v0 + v1 + v2 + v3;
            ss = fmaf(v0,v0,ss); ss = fmaf(v1,v1,ss);
            ss = fmaf(v2,v2,ss); ss = fmaf(v3,v3,ss);
        }
#pragma unroll
        for (int off = 1; off < 16; off <<= 1) {
            s  += __shfl_xor(s,  off);
            ss += __shfl_xor(ss, off);
        }
        const float mu   = s * inv;
        const float rsig = rsqrtf(ss * inv - mu * mu + LN_EPS);

        float acc = 0.f;
#pragma unroll
        for (int w5 = 0; w5 < 5; ++w5) {
            const int c = w5 * 64 + fl * 4;
            float4 g  = *(const float4*)&SG[c];
            float4 bb = *(const float4*)&SB[c];
            float4 w  = *(const float4*)&SW[c];
#pragma unroll
            for (int e = 0; e < 4; ++e) {
                float t0 = fmaf((h[w5*4+e] - mu) * rsig, (&g.x)[e], (&bb.x)[e]);
                t0 = t0 > 0.f ? t0 : __expf(t0) - 1.f;
                acc = fmaf(t0, (&w.x)[e], acc);
            }
        }
#pragma unroll
        for (int off = 1; off < 16; off <<= 1) acc += __shfl_xor(acc, off);

        if (fl == 0 && active) {
            const int jb = ii - KWIN < 0 ? 0 : ii - KWIN;
            const int n = rowstart(ii) + (j - jb);
            out[(size_t)b * NC + n] = acc + b2v;
            if (b == 0) {
                posout[2 * (size_t)n]     = (float)(ii + 1);
                posout[2 * (size_t)n + 1] = (float)(j + 1);
            }
        }
    }
}

// ---------------------------------------------------------------------------
extern "C" void kernel_launch(void* const* d_in, const int* in_sizes, int n_in,
                              void* d_out, int out_size, void* d_ws, size_t ws_size,
                              hipStream_t stream) {
    const float* h_e     = (const float*)d_in[0];
    const float* h_c     = (const float*)d_in[1];
    const float* h_share = (const float*)d_in[2];
    // d_in[3] = mask (unused)
    const float* pos_W   = (const float*)d_in[4];
    const float* W1      = (const float*)d_in[5];
    const float* b1      = (const float*)d_in[6];
    const float* ln_g    = (const float*)d_in[7];
    const float* ln_b    = (const float*)d_in[8];
    const float* W2      = (const float*)d_in[9];
    const float* b2      = (const float*)d_in[10];

    float* ws   = (float*)d_ws;
    float* prel = ws + PREL_OFF;
    short* Wb   = (short*)(ws + WB_OFF);

    float* out    = (float*)d_out;
    float* posout = out + BNC;

    prep_kernel<<<14 + (2 * WNPAD * WKSTR) / 256, 256, 0, stream>>>(
        pos_W, W1, b1, prel, Wb);

    fused_kernel<<<NB * (L_SEQ / ITILE), 512, 0, stream>>>(
        h_e, h_c, h_share, Wb, prel, ln_g, ln_b, W2, b2, out, posout);
}

// Round 9
// 139.771 us; speedup vs baseline: 1.3443x; 1.0870x over previous
//
#include <hip/hip_runtime.h>
#include <hip/hip_bf16.h>
#include <math.h>

// Problem constants
#define L_SEQ   1024
#define NB      8
#define H_DIM   300
#define KWIN    5
#define NREL    11          // 2K+1
#define PDIM    50
#define NC      11234       // band pair count for L=1024, K=5
#define BNC     (NB*NC)     // 89872
#define LN_EPS  1e-5f

#define KPAD    320         // K padded with zeros in [300,320)
#define WKSTR   320         // Wb k-stride (shorts)
#define WNPAD   320         // Wb padded n rows

#define ITILE   16          // i rows per block
#define HROWS   26          // hc halo rows: i0-5 .. i0+20
#define ZROW    42          // LDS zero row index
#define XROWS   43          // 0..15 he, 16..41 hc, 42 zero
#define XSTR    328         // X row stride in shorts
#define PRELSTR 320         // padded prel row stride (floats)
#define NPAIR   (ITILE*NREL)  // 176

// Workspace layout (float offsets)
#define PREL_OFF  0                         // 11*320 = 3520 -> pad 3584
#define WB_OFF    3584                      // 2*320*320 shorts = 102400 floats

typedef __attribute__((ext_vector_type(8))) short s16x8;
typedef __attribute__((ext_vector_type(4))) short s16x4;
typedef __attribute__((ext_vector_type(4))) float f32x4;

__device__ __forceinline__ short f2bf(float f) {
    unsigned u = __float_as_uint(f);
    u += 0x7fffu + ((u >> 16) & 1u);
    return (short)(u >> 16);
}
__device__ __forceinline__ float bf2f(short s) {
    return __uint_as_float(((unsigned)(unsigned short)s) << 16);
}

// band row start: first linear index n of row i
__device__ __forceinline__ int rowstart(int i) {
    if (i < 5)     return 6 * i + (i * (i - 1)) / 2;
    if (i <= 1018) return 40 + (i - 5) * 11;
    int d = i - 1019;
    return 11194 + d * 10 - (d * (d - 1)) / 2;
}

// ---------------------------------------------------------------------------
// Kernel 1: prep.
//  blocks 0..13   : prelP[r][h] (stride 320, zero pad h>=300)
//  blocks 14..813 : Wb[z][n][k] = bf16(W1[n][z*300+k]), zero-padded
__global__ __launch_bounds__(256) void prep_kernel(
    const float* __restrict__ pos_W, const float* __restrict__ W1,
    const float* __restrict__ b1, float* __restrict__ prel,
    short* __restrict__ Wb)
{
    if (blockIdx.x < 14) {
        __shared__ float semb[NREL * PDIM];
        for (int t = threadIdx.x; t < NREL * PDIM; t += 256) {
            int r = t / PDIM, d = t % PDIM;
            float acc = 0.f;
#pragma unroll
            for (int r2 = 0; r2 < NREL; ++r2) {
                float cnt = (float)(L_SEQ - abs(r2 - KWIN));
                int dr = r - r2;
                acc += cnt * expf(-(float)(dr * dr)) * pos_W[r2 * PDIM + d];
            }
            semb[t] = acc;
        }
        __syncthreads();
        int t = blockIdx.x * 256 + threadIdx.x;
        if (t < NREL * PRELSTR) {
            int r = t / PRELSTR, h = t % PRELSTR;
            float acc = 0.f;
            if (h < H_DIM) {
                acc = b1[h];
                const float* wrow = W1 + (size_t)h * 650 + 600;
                const float* em = semb + r * PDIM;
#pragma unroll 10
                for (int d = 0; d < PDIM; ++d) acc += wrow[d] * em[d];
            }
            prel[t] = acc;
        }
    } else {
        int id = (blockIdx.x - 14) * 256 + threadIdx.x;
        if (id < 2 * WNPAD * WKSTR) {
            int z = id / (WNPAD * WKSTR);
            int rem = id % (WNPAD * WKSTR);
            int n = rem / WKSTR, k = rem % WKSTR;
            float v = (n < H_DIM && k < H_DIM) ? W1[(size_t)n * 650 + z * H_DIM + k] : 0.f;
            Wb[id] = f2bf(v);
        }
    }
}

// ---------------------------------------------------------------------------
// Kernel 2: fused GEMM + epilogue. Block = (b, i-tile of 16). 512 threads.
// Grid 512. No min-waves cap (round-6 spill lesson).
__global__ __launch_bounds__(512) void fused_kernel(
    const float* __restrict__ h_e, const float* __restrict__ h_c,
    const float* __restrict__ h_share, const short* __restrict__ Wb,
    const float* __restrict__ prel,
    const float* __restrict__ ln_g, const float* __restrict__ ln_b,
    const float* __restrict__ W2, const float* __restrict__ b2,
    float* __restrict__ out, float* __restrict__ posout)
{
    __shared__ __align__(16) short X[XROWS * XSTR];   // 28208 B
    __shared__ __align__(16) float SG[PRELSTR];
    __shared__ __align__(16) float SB[PRELSTR];
    __shared__ __align__(16) float SW[PRELSTR];

    const int tid = threadIdx.x;
    const int b   = blockIdx.x >> 6;          // 64 i-tiles per batch
    const int i0  = (blockIdx.x & 63) * ITILE;

    const int wave = tid >> 6, lane = tid & 63;
    const int fr = lane & 15, fq = lane >> 4;
    const int wz  = wave >> 2;                // 0: he GEMM, 1: hc GEMM
    const int nsl = (wave & 3) * 80;
    const short* wbase = Wb + ((size_t)(wz * WNPAD + nsl + fr)) * WKSTR + fq * 8;

    // ---- B prefetch for k0=0: independent of staging, issue FIRST.
    s16x8 bf[5];
#pragma unroll
    for (int nt = 0; nt < 5; ++nt)
        bf[nt] = *(const s16x8*)(wbase + (size_t)nt * 16 * WKSTR);

    // ---- zero-fill: all rows cols [304,328) (43*3) + zero row cols [0,304) (38)
    for (int t = tid; t < 167; t += 512) {
        int row, c;
        if (t < 129) { row = t / 3;  c = 304 + (t % 3) * 8; }
        else         { row = ZROW;   c = (t - 129) * 8; }
        *(s16x8*)&X[row * XSTR + c] = (s16x8){0,0,0,0,0,0,0,0};
    }
    // ---- LN params to LDS (zero pad to 320)
    for (int t = tid; t < PRELSTR; t += 512) {
        bool v = t < H_DIM;
        SG[t] = v ? ln_g[t] : 0.f;
        SB[t] = v ? ln_b[t] : 0.f;
        SW[t] = v ? W2[t]   : 0.f;
    }
    // ---- stage 26 halo rows; h_share read once per row.
    //  X rows 0..15 = bf16(he+hs)[i0+r]; rows 16..41 = bf16(hc+hs)[i0-5+s]
    for (int t = tid; t < HROWS * 76; t += 512) {
        int s = t / 76, kc = (t % 76) * 4;
        int g = i0 - KWIN + s;
        bool valid = (kc < H_DIM) && (g >= 0) && (g < L_SEQ);
        float4 hs4 = make_float4(0.f,0.f,0.f,0.f), hc4 = hs4;
        size_t off = 0;
        if (valid) {
            off = ((size_t)b * L_SEQ + g) * H_DIM + kc;
            hs4 = *(const float4*)(h_share + off);
            hc4 = *(const float4*)(h_c + off);
        }
        s16x4 vc = { f2bf(hc4.x + hs4.x), f2bf(hc4.y + hs4.y),
                     f2bf(hc4.z + hs4.z), f2bf(hc4.w + hs4.w) };
        *(s16x4*)&X[(16 + s) * XSTR + kc] = vc;
        if (s >= 5 && s < 5 + ITILE) {         // he row: g = i0 + (s-5)
            float4 he4 = make_float4(0.f,0.f,0.f,0.f);
            if (valid) he4 = *(const float4*)(h_e + off);
            s16x4 ve = { f2bf(he4.x + hs4.x), f2bf(he4.y + hs4.y),
                         f2bf(he4.z + hs4.z), f2bf(he4.w + hs4.w) };
            *(s16x4*)&X[(s - 5) * XSTR + kc] = ve;
        }
    }
    __syncthreads();

    // ---- GEMM: wz0 waves: 1 m-frag (he rows 0..15); wz1: 2 m-frags (hc 16..41)
    const int mrow0 = wz ? (16 + fr) : fr;
    const int mrow1 = (fr < 10) ? (32 + fr) : ZROW;   // wz==1 only

    f32x4 acc0[5] = {};
    f32x4 acc1[5] = {};

    for (int k0 = 0; k0 < KPAD; k0 += 32) {
        // prefetch next B tile while current MFMAs run
        s16x8 bn[5];
        if (k0 + 32 < KPAD) {
#pragma unroll
            for (int nt = 0; nt < 5; ++nt)
                bn[nt] = *(const s16x8*)(wbase + (size_t)nt * 16 * WKSTR + k0 + 32);
        }
        s16x8 af0 = *(const s16x8*)&X[mrow0 * XSTR + k0 + fq * 8];
#pragma unroll
        for (int nt = 0; nt < 5; ++nt)
            acc0[nt] = __builtin_amdgcn_mfma_f32_16x16x32_bf16(af0, bf[nt], acc0[nt], 0, 0, 0);
        if (wz) {
            s16x8 af1 = *(const s16x8*)&X[mrow1 * XSTR + k0 + fq * 8];
#pragma unroll
            for (int nt = 0; nt < 5; ++nt)
                acc1[nt] = __builtin_amdgcn_mfma_f32_16x16x32_bf16(af1, bf[nt], acc1[nt], 0, 0, 0);
        }
        if (k0 + 32 < KPAD) {
#pragma unroll
            for (int nt = 0; nt < 5; ++nt) bf[nt] = bn[nt];
        }
    }
    __syncthreads();   // all waves done reading X inputs

    // ---- write results into X (bf16). C/D: col=fr(+16*nt+nsl), row=fq*4+r2
#pragma unroll
    for (int nt = 0; nt < 5; ++nt) {
        const int col = nsl + nt * 16 + fr;     // 0..319 (cols>=300 are zeros)
        if (!wz) {
#pragma unroll
            for (int r2 = 0; r2 < 4; ++r2)
                X[(fq * 4 + r2) * XSTR + col] = f2bf(acc0[nt][r2]);
        } else {
#pragma unroll
            for (int r2 = 0; r2 < 4; ++r2)
                X[(16 + fq * 4 + r2) * XSTR + col] = f2bf(acc0[nt][r2]);
#pragma unroll
            for (int r2 = 0; r2 < 4; ++r2) {
                int rw = 32 + fq * 4 + r2;
                if (rw < 42) X[rw * XSTR + col] = f2bf(acc1[nt][r2]);
            }
        }
    }
    __syncthreads();

    // ---- Epilogue: 2 pairs per 16-lane quad, 32 quads, 3 rounds (176 pairs).
    const int quad = lane >> 4, fl = lane & 15;
    const int qq = wave * 4 + quad;            // 0..31
    const float b2v = b2[0];
    const float inv = 1.f / (float)H_DIM;

    for (int round = 0; round < 3; ++round) {
        const int qb = round * 64 + qq * 2;
        int di[2], rr[2], jj[2], ii[2];
        bool act[2];
#pragma unroll
        for (int u = 0; u < 2; ++u) {
            int q = qb + u;
            int qc = q < NPAIR - 1 ? q : NPAIR - 1;
            di[u] = qc / NREL; rr[u] = qc % NREL;
            ii[u] = i0 + di[u];
            jj[u] = ii[u] - KWIN + rr[u];
            act[u] = (q < NPAIR) && (jj[u] >= 0) && (jj[u] < L_SEQ);
        }
        const int ea0 = di[0] * XSTR,             ea1 = di[1] * XSTR;
        const int ca0 = (16 + di[0] + rr[0]) * XSTR, ca1 = (16 + di[1] + rr[1]) * XSTR;
        const float* pr0 = prel + rr[0] * PRELSTR;
        const float* pr1 = prel + rr[1] * PRELSTR;

        float h0[20], h1[20];
        float s0 = 0.f, ss0 = 0.f, s1 = 0.f, ss1 = 0.f;
#pragma unroll
        for (int w5 = 0; w5 < 5; ++w5) {
            const int c = w5 * 64 + fl * 4;     // 0..316, zero-padded
            s16x4 a0 = *(const s16x4*)&X[ea0 + c];
            s16x4 d0 = *(const s16x4*)&X[ca0 + c];
            float4 p0 = *(const float4*)(pr0 + c);
            s16x4 a1 = *(const s16x4*)&X[ea1 + c];
            s16x4 d1 = *(const s16x4*)&X[ca1 + c];
            float4 p1 = *(const float4*)(pr1 + c);
#pragma unroll
            for (int e = 0; e < 4; ++e) {
                float v0 = bf2f(a0[e]) + bf2f(d0[e]) + (&p0.x)[e];
                float v1 = bf2f(a1[e]) + bf2f(d1[e]) + (&p1.x)[e];
                h0[w5*4+e] = v0; h1[w5*4+e] = v1;
                s0 += v0; ss0 = fmaf(v0, v0, ss0);
                s1 += v1; ss1 = fmaf(v1, v1, ss1);
            }
        }
#pragma unroll
        for (int off = 1; off < 16; off <<= 1) {
            s0  += __shfl_xor(s0,  off);
            s1  += __shfl_xor(s1,  off);
            ss0 += __shfl_xor(ss0, off);
            ss1 += __shfl_xor(ss1, off);
        }
        const float mu0   = s0 * inv;
        const float rsig0 = rsqrtf(ss0 * inv - mu0 * mu0 + LN_EPS);
        const float mu1   = s1 * inv;
        const float rsig1 = rsqrtf(ss1 * inv - mu1 * mu1 + LN_EPS);

        float acc0e = 0.f, acc1e = 0.f;
#pragma unroll
        for (int w5 = 0; w5 < 5; ++w5) {
            const int c = w5 * 64 + fl * 4;
            float4 g  = *(const float4*)&SG[c];
            float4 bb = *(const float4*)&SB[c];
            float4 w  = *(const float4*)&SW[c];
#pragma unroll
            for (int e = 0; e < 4; ++e) {
                float ge = (&g.x)[e], be = (&bb.x)[e], we = (&w.x)[e];
                float t0 = fmaf((h0[w5*4+e] - mu0) * rsig0, ge, be);
                float t1 = fmaf((h1[w5*4+e] - mu1) * rsig1, ge, be);
                t0 = t0 > 0.f ? t0 : __expf(t0) - 1.f;
                t1 = t1 > 0.f ? t1 : __expf(t1) - 1.f;
                acc0e = fmaf(t0, we, acc0e);
                acc1e = fmaf(t1, we, acc1e);
            }
        }
#pragma unroll
        for (int off = 1; off < 16; off <<= 1) {
            acc0e += __shfl_xor(acc0e, off);
            acc1e += __shfl_xor(acc1e, off);
        }

        if (fl == 0) {
#pragma unroll
            for (int u = 0; u < 2; ++u) {
                if (act[u]) {
                    const int jb = ii[u] - KWIN < 0 ? 0 : ii[u] - KWIN;
                    const int n = rowstart(ii[u]) + (jj[u] - jb);
                    out[(size_t)b * NC + n] = (u ? acc1e : acc0e) + b2v;
                    if (b == 0) {
                        posout[2 * (size_t)n]     = (float)(ii[u] + 1);
                        posout[2 * (size_t)n + 1] = (float)(jj[u] + 1);
                    }
                }
            }
        }
    }
}

// ---------------------------------------------------------------------------
extern "C" void kernel_launch(void* const* d_in, const int* in_sizes, int n_in,
                              void* d_out, int out_size, void* d_ws, size_t ws_size,
                              hipStream_t stream) {
    const float* h_e     = (const float*)d_in[0];
    const float* h_c     = (const float*)d_in[1];
    const float* h_share = (const float*)d_in[2];
    // d_in[3] = mask (unused)
    const float* pos_W   = (const float*)d_in[4];
    const float* W1      = (const float*)d_in[5];
    const float* b1      = (const float*)d_in[6];
    const float* ln_g    = (const float*)d_in[7];
    const float* ln_b    = (const float*)d_in[8];
    const float* W2      = (const float*)d_in[9];
    const float* b2      = (const float*)d_in[10];

    float* ws   = (float*)d_ws;
    float* prel = ws + PREL_OFF;
    short* Wb   = (short*)(ws + WB_OFF);

    float* out    = (float*)d_out;
    float* posout = out + BNC;

    prep_kernel<<<14 + (2 * WNPAD * WKSTR) / 256, 256, 0, stream>>>(
        pos_W, W1, b1, prel, Wb);

    fused_kernel<<<NB * (L_SEQ / ITILE), 512, 0, stream>>>(
        h_e, h_c, h_share, Wb, prel, ln_g, ln_b, W2, b2, out, posout);
}

// Round 10
// 135.221 us; speedup vs baseline: 1.3895x; 1.0336x over previous
//
#include <hip/hip_runtime.h>
#include <hip/hip_bf16.h>
#include <math.h>

// Problem constants
#define L_SEQ   1024
#define NB      8
#define H_DIM   300
#define KWIN    5
#define NREL    11          // 2K+1
#define PDIM    50
#define NC      11234       // band pair count for L=1024, K=5
#define BNC     (NB*NC)     // 89872
#define LN_EPS  1e-5f

#define KPAD    320         // K padded with zeros in [300,320)
#define WKSTR   320         // Wb k-stride (shorts)
#define WNPAD   320         // Wb padded n rows

#define ITILE   32          // i rows per block
#define HROWS   42          // hc halo rows: i0-5 .. i0+36
#define ZROW    74          // LDS zero row index
#define XROWS   75          // 0..31 he, 32..73 hc, 74 zero
#define XSTR    328         // X row stride in shorts
#define PRELSTR 320         // padded prel row stride (floats)
#define NPAIR   (ITILE*NREL)  // 352

// Workspace layout (float offsets)
#define PREL_OFF  0                         // 11*320 = 3520 -> pad 3584
#define WB_OFF    3584                      // 2*320*320 shorts = 102400 floats

typedef __attribute__((ext_vector_type(8))) short s16x8;
typedef __attribute__((ext_vector_type(4))) short s16x4;
typedef __attribute__((ext_vector_type(4))) float f32x4;

__device__ __forceinline__ short f2bf(float f) {
    unsigned u = __float_as_uint(f);
    u += 0x7fffu + ((u >> 16) & 1u);
    return (short)(u >> 16);
}
__device__ __forceinline__ float bf2f(short s) {
    return __uint_as_float(((unsigned)(unsigned short)s) << 16);
}

// band row start: first linear index n of row i
__device__ __forceinline__ int rowstart(int i) {
    if (i < 5)     return 6 * i + (i * (i - 1)) / 2;
    if (i <= 1018) return 40 + (i - 5) * 11;
    int d = i - 1019;
    return 11194 + d * 10 - (d * (d - 1)) / 2;
}

// ---------------------------------------------------------------------------
// Kernel 1: prep.
//  blocks 0..13   : prelP[r][h] (stride 320, zero pad h>=300)
//  blocks 14..813 : Wb[z][n][k] = bf16(W1[n][z*300+k]), zero-padded
__global__ __launch_bounds__(256) void prep_kernel(
    const float* __restrict__ pos_W, const float* __restrict__ W1,
    const float* __restrict__ b1, float* __restrict__ prel,
    short* __restrict__ Wb)
{
    if (blockIdx.x < 14) {
        __shared__ float semb[NREL * PDIM];
        for (int t = threadIdx.x; t < NREL * PDIM; t += 256) {
            int r = t / PDIM, d = t % PDIM;
            float acc = 0.f;
#pragma unroll
            for (int r2 = 0; r2 < NREL; ++r2) {
                float cnt = (float)(L_SEQ - abs(r2 - KWIN));
                int dr = r - r2;
                acc += cnt * expf(-(float)(dr * dr)) * pos_W[r2 * PDIM + d];
            }
            semb[t] = acc;
        }
        __syncthreads();
        int t = blockIdx.x * 256 + threadIdx.x;
        if (t < NREL * PRELSTR) {
            int r = t / PRELSTR, h = t % PRELSTR;
            float acc = 0.f;
            if (h < H_DIM) {
                acc = b1[h];
                const float* wrow = W1 + (size_t)h * 650 + 600;
                const float* em = semb + r * PDIM;
#pragma unroll 10
                for (int d = 0; d < PDIM; ++d) acc += wrow[d] * em[d];
            }
            prel[t] = acc;
        }
    } else {
        int id = (blockIdx.x - 14) * 256 + threadIdx.x;
        if (id < 2 * WNPAD * WKSTR) {
            int z = id / (WNPAD * WKSTR);
            int rem = id % (WNPAD * WKSTR);
            int n = rem / WKSTR, k = rem % WKSTR;
            float v = (n < H_DIM && k < H_DIM) ? W1[(size_t)n * 650 + z * H_DIM + k] : 0.f;
            Wb[id] = f2bf(v);
        }
    }
}

// ---------------------------------------------------------------------------
// Kernel 2: fused GEMM + epilogue. Block = (b, i-tile of 32). 1024 threads
// (16 waves), grid 256 = 1 block/CU -> 16 waves/CU from ONE block (50% occ
// ceiling vs round-5's 2x8=16 shared between 2 barrier-phased blocks).
// No B prefetch (round-9 VGPR lesson), no min-waves cap (round-6 spill lesson).
__global__ __launch_bounds__(1024) void fused_kernel(
    const float* __restrict__ h_e, const float* __restrict__ h_c,
    const float* __restrict__ h_share, const short* __restrict__ Wb,
    const float* __restrict__ prel,
    const float* __restrict__ ln_g, const float* __restrict__ ln_b,
    const float* __restrict__ W2, const float* __restrict__ b2,
    float* __restrict__ out, float* __restrict__ posout)
{
    __shared__ __align__(16) short X[XROWS * XSTR];   // 49200 B
    __shared__ __align__(16) float PL[NREL * PRELSTR];// 14080 B (prel)
    __shared__ __align__(16) float SG[PRELSTR];
    __shared__ __align__(16) float SB[PRELSTR];
    __shared__ __align__(16) float SW[PRELSTR];

    const int tid = threadIdx.x;
    const int b   = blockIdx.x >> 5;          // 32 i-tiles per batch
    const int i0  = (blockIdx.x & 31) * ITILE;

    // ---- zero-fill: all 75 rows cols [304,328) (75*3=225) + zero row [0,304) (38)
    for (int t = tid; t < 263; t += 1024) {
        int row, c;
        if (t < 225) { row = t / 3;  c = 304 + (t % 3) * 8; }
        else         { row = ZROW;   c = (t - 225) * 8; }
        *(s16x8*)&X[row * XSTR + c] = (s16x8){0,0,0,0,0,0,0,0};
    }
    // ---- prel -> LDS (880 float4 chunks)
    for (int t = tid; t < NREL * 80; t += 1024) {
        int r = t / 80, kc = (t % 80) * 4;
        *(float4*)&PL[r * PRELSTR + kc] = *(const float4*)(prel + r * PRELSTR + kc);
    }
    // ---- LN params to LDS (zero pad to 320)
    for (int t = tid; t < PRELSTR; t += 1024) {
        bool v = t < H_DIM;
        SG[t] = v ? ln_g[t] : 0.f;
        SB[t] = v ? ln_b[t] : 0.f;
        SW[t] = v ? W2[t]   : 0.f;
    }
    // ---- stage 42 halo rows; h_share read once per row.
    //  X rows 32..73 = bf16(hc+hs)[i0-5+s]; rows 0..31 = bf16(he+hs)[i0+(s-5)]
    for (int t = tid; t < HROWS * 76; t += 1024) {
        int s = t / 76, kc = (t % 76) * 4;
        int g = i0 - KWIN + s;
        bool valid = (kc < H_DIM) && (g >= 0) && (g < L_SEQ);
        float4 hs4 = make_float4(0.f,0.f,0.f,0.f), hc4 = hs4;
        size_t off = 0;
        if (valid) {
            off = ((size_t)b * L_SEQ + g) * H_DIM + kc;
            hs4 = *(const float4*)(h_share + off);
            hc4 = *(const float4*)(h_c + off);
        }
        s16x4 vc = { f2bf(hc4.x + hs4.x), f2bf(hc4.y + hs4.y),
                     f2bf(hc4.z + hs4.z), f2bf(hc4.w + hs4.w) };
        *(s16x4*)&X[(32 + s) * XSTR + kc] = vc;
        if (s >= 5 && s < 5 + ITILE) {         // he row: g = i0 + (s-5)
            float4 he4 = make_float4(0.f,0.f,0.f,0.f);
            if (valid) he4 = *(const float4*)(h_e + off);
            s16x4 ve = { f2bf(he4.x + hs4.x), f2bf(he4.y + hs4.y),
                         f2bf(he4.z + hs4.z), f2bf(he4.w + hs4.w) };
            *(s16x4*)&X[(s - 5) * XSTR + kc] = ve;
        }
    }
    __syncthreads();

    // ---- GEMM. 16 waves = (wz, nsl, mh).
    //  wz0 (he, 32 rows): mh picks rows 0..15 / 16..31 (1 frag).
    //  wz1 (hc, 42 rows): mh0 -> rows 32..47 & 48..63 (2 frags);
    //                     mh1 -> rows 64..73 + zero-row clamp (1 frag).
    const int wave = tid >> 6, lane = tid & 63;
    const int fr = lane & 15, fq = lane >> 4;
    const int wz  = wave >> 3;
    const int nsl = ((wave >> 1) & 3) * 80;
    const int mh  = wave & 1;
    const short* wbase = Wb + ((size_t)(wz * WNPAD + nsl + fr)) * WKSTR + fq * 8;

    const int mrow0 = wz ? (mh ? ((fr < 10) ? 64 + fr : ZROW) : 32 + fr)
                         : mh * 16 + fr;
    const int mrow1 = 48 + fr;                 // only wz1&&mh0
    const bool two = (wz == 1) && (mh == 0);

    f32x4 acc0[5] = {};
    f32x4 acc1[5] = {};

    for (int k0 = 0; k0 < KPAD; k0 += 32) {
        s16x8 bf[5];
#pragma unroll
        for (int nt = 0; nt < 5; ++nt)
            bf[nt] = *(const s16x8*)(wbase + (size_t)nt * 16 * WKSTR + k0);
        s16x8 af0 = *(const s16x8*)&X[mrow0 * XSTR + k0 + fq * 8];
#pragma unroll
        for (int nt = 0; nt < 5; ++nt)
            acc0[nt] = __builtin_amdgcn_mfma_f32_16x16x32_bf16(af0, bf[nt], acc0[nt], 0, 0, 0);
        if (two) {
            s16x8 af1 = *(const s16x8*)&X[mrow1 * XSTR + k0 + fq * 8];
#pragma unroll
            for (int nt = 0; nt < 5; ++nt)
                acc1[nt] = __builtin_amdgcn_mfma_f32_16x16x32_bf16(af1, bf[nt], acc1[nt], 0, 0, 0);
        }
    }
    __syncthreads();   // all waves done reading X inputs

    // ---- write results into X (bf16). C/D: col = nsl+nt*16+fr, row = fq*4+r2.
    // Cols >= 300 compute to 0 (Wb zero-padded) so unconditional col writes
    // keep the pad zero.
#pragma unroll
    for (int nt = 0; nt < 5; ++nt) {
        const int col = nsl + nt * 16 + fr;
        if (!wz) {
#pragma unroll
            for (int r2 = 0; r2 < 4; ++r2)
                X[(mh * 16 + fq * 4 + r2) * XSTR + col] = f2bf(acc0[nt][r2]);
        } else if (!mh) {
#pragma unroll
            for (int r2 = 0; r2 < 4; ++r2) {
                X[(32 + fq * 4 + r2) * XSTR + col] = f2bf(acc0[nt][r2]);
                X[(48 + fq * 4 + r2) * XSTR + col] = f2bf(acc1[nt][r2]);
            }
        } else {
#pragma unroll
            for (int r2 = 0; r2 < 4; ++r2) {
                int rw = 64 + fq * 4 + r2;
                if (rw < 64 + 10) X[rw * XSTR + col] = f2bf(acc0[nt][r2]);
            }
        }
    }
    __syncthreads();

    // ---- Epilogue: 1 pair per 16-lane quad, 64 quads, 6 rounds (352 pairs).
    const int quad = lane >> 4, fl = lane & 15;
    const int qq = wave * 4 + quad;            // 0..63
    const float b2v = b2[0];
    const float inv = 1.f / (float)H_DIM;

    for (int round = 0; round < 6; ++round) {
        const int q = round * 64 + qq;          // 0..383
        const int qc = q < NPAIR - 1 ? q : NPAIR - 1;
        const int di = qc / NREL, rr = qc % NREL;
        const int ii = i0 + di, j = ii - KWIN + rr;
        const bool active = (q < NPAIR) && (j >= 0) && (j < L_SEQ);

        const int ea = di * XSTR;               // he rows 0..31
        const int ca = (32 + di + rr) * XSTR;   // hc rows 32..73
        const float* prow = PL + rr * PRELSTR;

        float h[20];
        float s = 0.f, ss = 0.f;
#pragma unroll
        for (int w5 = 0; w5 < 5; ++w5) {
            const int c = w5 * 64 + fl * 4;     // 0..316, zero-padded
            s16x4 a0 = *(const s16x4*)&X[ea + c];
            s16x4 d0 = *(const s16x4*)&X[ca + c];
            float4 p0 = *(const float4*)(prow + c);
#pragma unroll
            for (int e = 0; e < 4; ++e) {
                float v = bf2f(a0[e]) + bf2f(d0[e]) + (&p0.x)[e];
                h[w5*4+e] = v;
                s += v; ss = fmaf(v, v, ss);
            }
        }
#pragma unroll
        for (int off = 1; off < 16; off <<= 1) {
            s  += __shfl_xor(s,  off);
            ss += __shfl_xor(ss, off);
        }
        const float mu   = s * inv;
        const float rsig = rsqrtf(ss * inv - mu * mu + LN_EPS);

        float acc = 0.f;
#pragma unroll
        for (int w5 = 0; w5 < 5; ++w5) {
            const int c = w5 * 64 + fl * 4;
            float4 g  = *(const float4*)&SG[c];
            float4 bb = *(const float4*)&SB[c];
            float4 w  = *(const float4*)&SW[c];
#pragma unroll
            for (int e = 0; e < 4; ++e) {
                float t0 = fmaf((h[w5*4+e] - mu) * rsig, (&g.x)[e], (&bb.x)[e]);
                t0 = t0 > 0.f ? t0 : __expf(t0) - 1.f;
                acc = fmaf(t0, (&w.x)[e], acc);
            }
        }
#pragma unroll
        for (int off = 1; off < 16; off <<= 1) acc += __shfl_xor(acc, off);

        if (fl == 0 && active) {
            const int jb = ii - KWIN < 0 ? 0 : ii - KWIN;
            const int n = rowstart(ii) + (j - jb);
            out[(size_t)b * NC + n] = acc + b2v;
            if (b == 0) {
                posout[2 * (size_t)n]     = (float)(ii + 1);
                posout[2 * (size_t)n + 1] = (float)(j + 1);
            }
        }
    }
}

// ---------------------------------------------------------------------------
extern "C" void kernel_launch(void* const* d_in, const int* in_sizes, int n_in,
                              void* d_out, int out_size, void* d_ws, size_t ws_size,
                              hipStream_t stream) {
    const float* h_e     = (const float*)d_in[0];
    const float* h_c     = (const float*)d_in[1];
    const float* h_share = (const float*)d_in[2];
    // d_in[3] = mask (unused)
    const float* pos_W   = (const float*)d_in[4];
    const float* W1      = (const float*)d_in[5];
    const float* b1      = (const float*)d_in[6];
    const float* ln_g    = (const float*)d_in[7];
    const float* ln_b    = (const float*)d_in[8];
    const float* W2      = (const float*)d_in[9];
    const float* b2      = (const float*)d_in[10];

    float* ws   = (float*)d_ws;
    float* prel = ws + PREL_OFF;
    short* Wb   = (short*)(ws + WB_OFF);

    float* out    = (float*)d_out;
    float* posout = out + BNC;

    prep_kernel<<<14 + (2 * WNPAD * WKSTR) / 256, 256, 0, stream>>>(
        pos_W, W1, b1, prel, Wb);

    fused_kernel<<<NB * (L_SEQ / ITILE), 1024, 0, stream>>>(
        h_e, h_c, h_share, Wb, prel, ln_g, ln_b, W2, b2, out, posout);
}